// Round 1
// baseline (493.414 us; speedup 1.0000x reference)
//
#include <hip/hip_runtime.h>
#include <math.h>

// Problem constants
constexpr int NB = 2, HH = 128, WW = 128, CC = 256, GG = 4, GC = 64;
constexpr int PP = 9, OMW = 108;            // om width = G*P*3 = 108
constexpr int MM = NB * HH * WW;            // 32768 pixels

// ---------------------------------------------------------------------------
// Depthwise 3x3 conv (pad 1) + bias:  ctx = dwconv(context_info) + dw_bias
// One thread per (pixel, 4-channel group). NHWC layout -> float4 coalesced.
// ---------------------------------------------------------------------------
__global__ __launch_bounds__(256) void dwconv_kernel(
    const float* __restrict__ x, const float* __restrict__ k,
    const float* __restrict__ b, float* __restrict__ y) {
  int gid = blockIdx.x * 256 + threadIdx.x;  // over MM * (CC/4)
  int q = gid & 63;
  int m = gid >> 6;
  int c = q * 4;
  int w = m & 127, h = (m >> 7) & 127, n = m >> 14;
  float4 acc = *(const float4*)&b[c];
#pragma unroll
  for (int dy = 0; dy < 3; ++dy) {
    int yy = h + dy - 1;
    if (yy < 0 || yy >= HH) continue;
#pragma unroll
    for (int dx = 0; dx < 3; ++dx) {
      int xx = w + dx - 1;
      if (xx < 0 || xx >= WW) continue;
      float4 v = *(const float4*)&x[(((size_t)n * HH + yy) * WW + xx) * CC + c];
      float4 kk = *(const float4*)&k[(dy * 3 + dx) * CC + c];
      acc.x += v.x * kk.x;
      acc.y += v.y * kk.y;
      acc.z += v.z * kk.z;
      acc.w += v.w * kk.w;
    }
  }
  *(float4*)&y[(size_t)m * CC + c] = acc;
}

// ---------------------------------------------------------------------------
// f32 GEMM:  Co[M x NOUT] = A[M x 256] * Bw[256 x NOUT] (+ bias) (+ LN+GELU)
// BM=64 rows/block, BN columns staged (NOUT<=BN, zero-padded), BK=16.
// 256 threads: pm = t&15 (4 rows each), pn = t>>4 (TN=BN/16 cols each).
// Register tile 4 x TN -> FMA-bound, LDS reads ~0.5x FMA cycles.
// ---------------------------------------------------------------------------
template <int BN, int NOUT, bool HAS_BIAS, bool LN>
__global__ __launch_bounds__(256) void gemm_k(
    const float* __restrict__ A, const float* __restrict__ Bw,
    const float* __restrict__ bias, float* __restrict__ Co,
    const float* __restrict__ lng, const float* __restrict__ lnb) {
  constexpr int BK = 16, BM = 64, TN = BN / 16;
  __shared__ float As[BK][BM];
  __shared__ float Bs[BK][BN];
  const int t = threadIdx.x;
  const int mb = blockIdx.x * BM;
  const int pm = t & 15, pn = t >> 4;

  float acc[4][TN];
#pragma unroll
  for (int i = 0; i < 4; ++i)
#pragma unroll
    for (int j = 0; j < TN; ++j) acc[i][j] = 0.f;

  const int am = t >> 2, ak = (t & 3) * 4;  // A staging map

  for (int ks = 0; ks < 256; ks += BK) {
    // Stage A tile (transpose to k-major)
    float4 av = *(const float4*)&A[((size_t)(mb + am)) * 256 + ks + ak];
    As[ak + 0][am] = av.x;
    As[ak + 1][am] = av.y;
    As[ak + 2][am] = av.z;
    As[ak + 3][am] = av.w;
    // Stage B tile
    if constexpr (NOUT == BN) {
      int n4 = (t & 63) * 4, kk0 = t >> 6;
#pragma unroll
      for (int i = 0; i < BK / 4; ++i)
        *(float4*)&Bs[kk0 + 4 * i][n4] =
            *(const float4*)&Bw[((size_t)(ks + kk0 + 4 * i)) * NOUT + n4];
    } else {
#pragma unroll
      for (int i = 0; i < BK * BN / 256; ++i) {
        int idx = t + 256 * i;
        int kk = idx / BN, n = idx % BN;
        Bs[kk][n] = (n < NOUT) ? Bw[((size_t)(ks + kk)) * NOUT + n] : 0.f;
      }
    }
    __syncthreads();
#pragma unroll
    for (int kk = 0; kk < BK; ++kk) {
      float4 a = *(const float4*)&As[kk][pm * 4];
      float aa[4] = {a.x, a.y, a.z, a.w};
      float bv[TN];
#pragma unroll
      for (int j = 0; j < TN; j += 4)
        *(float4*)&bv[j] = *(const float4*)&Bs[kk][pn * TN + j];
#pragma unroll
      for (int i = 0; i < 4; ++i)
#pragma unroll
        for (int j = 0; j < TN; ++j) acc[i][j] += aa[i] * bv[j];
    }
    __syncthreads();
  }

  if constexpr (LN) {
    // Per-pixel LayerNorm over full 256-col row + exact GELU
    __shared__ float red[2][16][64];
    __shared__ float mu_s[64], rs_s[64];
#pragma unroll
    for (int i = 0; i < 4; ++i) {
      float s = 0.f, ss = 0.f;
#pragma unroll
      for (int j = 0; j < TN; ++j) {
        float v = acc[i][j];
        s += v;
        ss += v * v;
      }
      red[0][pn][pm * 4 + i] = s;
      red[1][pn][pm * 4 + i] = ss;
    }
    __syncthreads();
    if (t < 64) {
      float s = 0.f, ss = 0.f;
#pragma unroll
      for (int p = 0; p < 16; ++p) {
        s += red[0][p][t];
        ss += red[1][p][t];
      }
      float mu = s * (1.f / 256.f);
      float var = ss * (1.f / 256.f) - mu * mu;
      mu_s[t] = mu;
      rs_s[t] = rsqrtf(var + 1e-5f);
    }
    __syncthreads();
#pragma unroll
    for (int i = 0; i < 4; ++i) {
      int row = mb + pm * 4 + i;
      float mu = mu_s[pm * 4 + i], rs = rs_s[pm * 4 + i];
      float o[TN];
#pragma unroll
      for (int j = 0; j < TN; ++j) {
        int col = pn * TN + j;
        float v = (acc[i][j] - mu) * rs * lng[col] + lnb[col];
        o[j] = 0.5f * v * (1.f + erff(v * 0.70710678118654752f));
      }
#pragma unroll
      for (int j = 0; j < TN; j += 4)
        *(float4*)&Co[(size_t)row * NOUT + pn * TN + j] = *(float4*)&o[j];
    }
  } else {
#pragma unroll
    for (int i = 0; i < 4; ++i) {
      int row = mb + pm * 4 + i;
#pragma unroll
      for (int j = 0; j < TN; ++j) {
        int col = pn * TN + j;
        if (col < NOUT) {
          float v = acc[i][j];
          if constexpr (HAS_BIAS) v += bias[col];
          Co[(size_t)row * NOUT + col] = v;
        }
      }
    }
  }
}

// ---------------------------------------------------------------------------
// Deformable bilinear sampling + mask-weighted sum over P taps.
// One wave per (pixel, group); lane = channel within group -> 256B coalesced
// gathers. Padded border is zero and invalid taps have weight 0, so a corner
// contributes iff its padded coords are in [1,128]^2 (fetch from unpadded).
// ---------------------------------------------------------------------------
__device__ __forceinline__ float fetchv(const float* vb, int x, int y) {
  if (x < 1 || x > WW || y < 1 || y > HH) return 0.f;
  return vb[(((size_t)(y - 1)) * WW + (x - 1)) * CC];
}

__global__ __launch_bounds__(256) void sample_kernel(
    const float* __restrict__ val, const float* __restrict__ om,
    float* __restrict__ out) {
  int m = blockIdx.x;
  int g = threadIdx.x >> 6;
  int lane = threadIdx.x & 63;
  int w = m & 127, h = (m >> 7) & 127, n = m >> 14;
  const float* omp = om + (size_t)m * OMW + g * 27;
  const float* vbase = val + ((size_t)n * HH * WW) * CC + g * GC + lane;
  float bx = (float)(w + 1), by = (float)(h + 1);
  float acc = 0.f;
#pragma unroll
  for (int p = 0; p < PP; ++p) {
    float ox = omp[2 * p], oy = omp[2 * p + 1], mk = omp[18 + p];
    float kx = (float)(p % 3 - 1), ky = (float)(p / 3 - 1);
    float px = bx + 0.5f * (kx + ox);
    float py = by + 0.5f * (ky + oy);
    float x0f = floorf(px), y0f = floorf(py);
    int x0 = (int)x0f, y0 = (int)y0f;
    float wx1 = px - x0f, wy1 = py - y0f;
    float wx0 = 1.f - wx1, wy0 = 1.f - wy1;
    float s = wx0 * wy0 * fetchv(vbase, x0, y0) +
              wx1 * wy0 * fetchv(vbase, x0 + 1, y0) +
              wx0 * wy1 * fetchv(vbase, x0, y0 + 1) +
              wx1 * wy1 * fetchv(vbase, x0 + 1, y0 + 1);
    acc += mk * s;
  }
  out[(size_t)m * CC + g * GC + lane] = acc;
}

// ---------------------------------------------------------------------------
extern "C" void kernel_launch(void* const* d_in, const int* in_sizes, int n_in,
                              void* d_out, int out_size, void* d_ws,
                              size_t ws_size, hipStream_t stream) {
  (void)in_sizes;
  (void)n_in;
  (void)out_size;
  (void)ws_size;
  const float* sampled = (const float*)d_in[0];
  const float* ctxin = (const float*)d_in[1];
  const float* W_in = (const float*)d_in[2];
  const float* b_in = (const float*)d_in[3];
  const float* dwk = (const float*)d_in[4];
  const float* dwb = (const float*)d_in[5];
  const float* W_om = (const float*)d_in[6];
  const float* b_om = (const float*)d_in[7];
  const float* W_out = (const float*)d_in[8];
  const float* lng = (const float*)d_in[9];
  const float* lnb = (const float*)d_in[10];
  float* out = (float*)d_out;

  float* ws = (float*)d_ws;
  float* value = ws;                          // MM*256 floats
  float* omb = value + (size_t)MM * CC;       // MM*108 floats
  float* ctx_dcn = omb + (size_t)MM * OMW;    // MM*256 floats (ctx, then dcn)

  // 1. depthwise conv -> ctx
  dwconv_kernel<<<MM * 64 / 256, 256, 0, stream>>>(ctxin, dwk, dwb, ctx_dcn);
  // 2. om = ctx @ W_om + b_om
  gemm_k<128, 108, true, false>
      <<<MM / 64, 256, 0, stream>>>(ctx_dcn, W_om, b_om, omb, nullptr, nullptr);
  // 3. value = sampled_feat @ W_in + b_in
  gemm_k<256, 256, true, false>
      <<<MM / 64, 256, 0, stream>>>(sampled, W_in, b_in, value, nullptr, nullptr);
  // 4. deformable sampling -> dcn (reuses ctx buffer)
  sample_kernel<<<MM, 256, 0, stream>>>(value, omb, ctx_dcn);
  // 5. out = LN(dcn @ W_out) -> GELU
  gemm_k<256, 256, false, true>
      <<<MM / 64, 256, 0, stream>>>(ctx_dcn, W_out, nullptr, out, lng, lnb);
}

// Round 2
// 388.124 us; speedup vs baseline: 1.2713x; 1.2713x over previous
//
#include <hip/hip_runtime.h>
#include <math.h>

// Problem constants
constexpr int NB = 2, HH = 128, WW = 128, CC = 256, GG = 4, GC = 64;
constexpr int PP = 9, OMW = 108;            // om width = G*P*3 = 108
constexpr int MM = NB * HH * WW;            // 32768 pixels

// ---------------------------------------------------------------------------
// Depthwise 3x3 conv (pad 1) + bias:  ctx = dwconv(context_info) + dw_bias
// One thread per (pixel, 4-channel group). NHWC layout -> float4 coalesced.
// ---------------------------------------------------------------------------
__global__ __launch_bounds__(256) void dwconv_kernel(
    const float* __restrict__ x, const float* __restrict__ k,
    const float* __restrict__ b, float* __restrict__ y) {
  int gid = blockIdx.x * 256 + threadIdx.x;  // over MM * (CC/4)
  int q = gid & 63;
  int m = gid >> 6;
  int c = q * 4;
  int w = m & 127, h = (m >> 7) & 127, n = m >> 14;
  float4 acc = *(const float4*)&b[c];
#pragma unroll
  for (int dy = 0; dy < 3; ++dy) {
    int yy = h + dy - 1;
    if (yy < 0 || yy >= HH) continue;
#pragma unroll
    for (int dx = 0; dx < 3; ++dx) {
      int xx = w + dx - 1;
      if (xx < 0 || xx >= WW) continue;
      float4 v = *(const float4*)&x[(((size_t)n * HH + yy) * WW + xx) * CC + c];
      float4 kk = *(const float4*)&k[(dy * 3 + dx) * CC + c];
      acc.x += v.x * kk.x;
      acc.y += v.y * kk.y;
      acc.z += v.z * kk.z;
      acc.w += v.w * kk.w;
    }
  }
  *(float4*)&y[(size_t)m * CC + c] = acc;
}

// ---------------------------------------------------------------------------
// f32 GEMM:  Co[M x NOUT] = A[M x 256] * Bw[256 x NOUT] (+ bias) (+ LN+GELU)
// BM=64 rows/block, BN columns staged (NOUT<=BN, zero-padded), BK=16.
// 256 threads: pm = t&15 (4 rows each), pn = t>>4 (TN=BN/16 cols each).
// ---------------------------------------------------------------------------
template <int BN, int NOUT, bool HAS_BIAS, bool LN>
__global__ __launch_bounds__(256) void gemm_k(
    const float* __restrict__ A, const float* __restrict__ Bw,
    const float* __restrict__ bias, float* __restrict__ Co,
    const float* __restrict__ lng, const float* __restrict__ lnb) {
  constexpr int BK = 16, BM = 64, TN = BN / 16;
  __shared__ float As[BK][BM];
  __shared__ float Bs[BK][BN];
  const int t = threadIdx.x;
  const int mb = blockIdx.x * BM;
  const int pm = t & 15, pn = t >> 4;

  float acc[4][TN];
#pragma unroll
  for (int i = 0; i < 4; ++i)
#pragma unroll
    for (int j = 0; j < TN; ++j) acc[i][j] = 0.f;

  const int am = t >> 2, ak = (t & 3) * 4;  // A staging map

  for (int ks = 0; ks < 256; ks += BK) {
    // Stage A tile (transpose to k-major)
    float4 av = *(const float4*)&A[((size_t)(mb + am)) * 256 + ks + ak];
    As[ak + 0][am] = av.x;
    As[ak + 1][am] = av.y;
    As[ak + 2][am] = av.z;
    As[ak + 3][am] = av.w;
    // Stage B tile
    if constexpr (NOUT == BN) {
      int n4 = (t & 63) * 4, kk0 = t >> 6;
#pragma unroll
      for (int i = 0; i < BK / 4; ++i)
        *(float4*)&Bs[kk0 + 4 * i][n4] =
            *(const float4*)&Bw[((size_t)(ks + kk0 + 4 * i)) * NOUT + n4];
    } else {
#pragma unroll
      for (int i = 0; i < BK * BN / 256; ++i) {
        int idx = t + 256 * i;
        int kk = idx / BN, n = idx % BN;
        Bs[kk][n] = (n < NOUT) ? Bw[((size_t)(ks + kk)) * NOUT + n] : 0.f;
      }
    }
    __syncthreads();
#pragma unroll
    for (int kk = 0; kk < BK; ++kk) {
      float4 a = *(const float4*)&As[kk][pm * 4];
      float aa[4] = {a.x, a.y, a.z, a.w};
      float bv[TN];
#pragma unroll
      for (int j = 0; j < TN; j += 4)
        *(float4*)&bv[j] = *(const float4*)&Bs[kk][pn * TN + j];
#pragma unroll
      for (int i = 0; i < 4; ++i)
#pragma unroll
        for (int j = 0; j < TN; ++j) acc[i][j] += aa[i] * bv[j];
    }
    __syncthreads();
  }

  if constexpr (LN) {
    // Per-pixel LayerNorm over full 256-col row + exact GELU
    __shared__ float red[2][16][64];
    __shared__ float mu_s[64], rs_s[64];
#pragma unroll
    for (int i = 0; i < 4; ++i) {
      float s = 0.f, ss = 0.f;
#pragma unroll
      for (int j = 0; j < TN; ++j) {
        float v = acc[i][j];
        s += v;
        ss += v * v;
      }
      red[0][pn][pm * 4 + i] = s;
      red[1][pn][pm * 4 + i] = ss;
    }
    __syncthreads();
    if (t < 64) {
      float s = 0.f, ss = 0.f;
#pragma unroll
      for (int p = 0; p < 16; ++p) {
        s += red[0][p][t];
        ss += red[1][p][t];
      }
      float mu = s * (1.f / 256.f);
      float var = ss * (1.f / 256.f) - mu * mu;
      mu_s[t] = mu;
      rs_s[t] = rsqrtf(var + 1e-5f);
    }
    __syncthreads();
#pragma unroll
    for (int i = 0; i < 4; ++i) {
      int row = mb + pm * 4 + i;
      float mu = mu_s[pm * 4 + i], rs = rs_s[pm * 4 + i];
      float o[TN];
#pragma unroll
      for (int j = 0; j < TN; ++j) {
        int col = pn * TN + j;
        float v = (acc[i][j] - mu) * rs * lng[col] + lnb[col];
        o[j] = 0.5f * v * (1.f + erff(v * 0.70710678118654752f));
      }
#pragma unroll
      for (int j = 0; j < TN; j += 4)
        *(float4*)&Co[(size_t)row * NOUT + pn * TN + j] = *(float4*)&o[j];
    }
  } else {
#pragma unroll
    for (int i = 0; i < 4; ++i) {
      int row = mb + pm * 4 + i;
#pragma unroll
      for (int j = 0; j < TN; ++j) {
        int col = pn * TN + j;
        if (col < NOUT) {
          float v = acc[i][j];
          if constexpr (HAS_BIAS) v += bias[col];
          Co[(size_t)row * NOUT + col] = v;
        }
      }
    }
  }
}

// ---------------------------------------------------------------------------
// Deformable bilinear sampling + mask-weighted sum over P taps.
// One thread per (pixel, channel-quad): float4 gathers, one wave = one pixel
// (all 4 groups as 16-lane clusters). All-int32 address math; branchless
// clamp + valid-select. Padded border is zero and invalid taps have weight 0,
// so a corner contributes iff padded coords in [1,128]^2 (read unpadded).
// ---------------------------------------------------------------------------
__global__ __launch_bounds__(256) void sample_kernel(
    const float* __restrict__ val, const float* __restrict__ om,
    float* __restrict__ out) {
  int gid = blockIdx.x * 256 + threadIdx.x;  // over MM * 64
  int q = gid & 63;   // channel-quad: channels 4q..4q+3
  int m = gid >> 6;   // pixel
  int g = q >> 4;     // group
  int w = m & 127, h = (m >> 7) & 127, n = m >> 14;
  const float* omp = om + m * OMW + g * 27;
  const float* vb = val + (n << 22) + (q << 2);  // n*H*W*C + 4q
  float bx = (float)(w + 1), by = (float)(h + 1);
  float4 acc = make_float4(0.f, 0.f, 0.f, 0.f);

#pragma unroll
  for (int p = 0; p < PP; ++p) {
    float px = bx + 0.5f * ((float)(p % 3 - 1) + omp[2 * p]);
    float py = by + 0.5f * ((float)(p / 3 - 1) + omp[2 * p + 1]);
    float mk = omp[18 + p];
    float x0f = floorf(px), y0f = floorf(py);
    int x0 = (int)x0f, y0 = (int)y0f;
    float wx1 = px - x0f, wy1 = py - y0f;
    float wx0 = 1.f - wx1, wy0 = 1.f - wy1;
    float4 s = make_float4(0.f, 0.f, 0.f, 0.f);
#define CORNER(XC, YC, WT)                                            \
  {                                                                   \
    int xc = (XC), yc = (YC);                                         \
    int xi = min(max(xc, 1), 128), yi = min(max(yc, 1), 128);         \
    float wt = ((xc == xi) && (yc == yi)) ? (WT) : 0.f;               \
    const float4 v =                                                  \
        *(const float4*)&vb[(((yi - 1) << 7) + (xi - 1)) << 8];       \
    s.x += v.x * wt;                                                  \
    s.y += v.y * wt;                                                  \
    s.z += v.z * wt;                                                  \
    s.w += v.w * wt;                                                  \
  }
    CORNER(x0, y0, wx0 * wy0);
    CORNER(x0 + 1, y0, wx1 * wy0);
    CORNER(x0, y0 + 1, wx0 * wy1);
    CORNER(x0 + 1, y0 + 1, wx1 * wy1);
#undef CORNER
    acc.x += mk * s.x;
    acc.y += mk * s.y;
    acc.z += mk * s.z;
    acc.w += mk * s.w;
  }
  *(float4*)&out[((size_t)m << 8) + (q << 2)] = acc;
}

// ---------------------------------------------------------------------------
extern "C" void kernel_launch(void* const* d_in, const int* in_sizes, int n_in,
                              void* d_out, int out_size, void* d_ws,
                              size_t ws_size, hipStream_t stream) {
  (void)in_sizes;
  (void)n_in;
  (void)out_size;
  (void)ws_size;
  const float* sampled = (const float*)d_in[0];
  const float* ctxin = (const float*)d_in[1];
  const float* W_in = (const float*)d_in[2];
  const float* b_in = (const float*)d_in[3];
  const float* dwk = (const float*)d_in[4];
  const float* dwb = (const float*)d_in[5];
  const float* W_om = (const float*)d_in[6];
  const float* b_om = (const float*)d_in[7];
  const float* W_out = (const float*)d_in[8];
  const float* lng = (const float*)d_in[9];
  const float* lnb = (const float*)d_in[10];
  float* out = (float*)d_out;

  float* ws = (float*)d_ws;
  float* value = ws;                          // MM*256 floats
  float* omb = value + (size_t)MM * CC;       // MM*108 floats
  float* ctx_dcn = omb + (size_t)MM * OMW;    // MM*256 floats (ctx, then dcn)

  // 1. depthwise conv -> ctx
  dwconv_kernel<<<MM * 64 / 256, 256, 0, stream>>>(ctxin, dwk, dwb, ctx_dcn);
  // 2. om = ctx @ W_om + b_om
  gemm_k<128, 108, true, false>
      <<<MM / 64, 256, 0, stream>>>(ctx_dcn, W_om, b_om, omb, nullptr, nullptr);
  // 3. value = sampled_feat @ W_in + b_in
  gemm_k<256, 256, true, false>
      <<<MM / 64, 256, 0, stream>>>(sampled, W_in, b_in, value, nullptr, nullptr);
  // 4. deformable sampling -> dcn (reuses ctx buffer)
  sample_kernel<<<MM * 64 / 256, 256, 0, stream>>>(value, omb, ctx_dcn);
  // 5. out = LN(dcn @ W_out) -> GELU
  gemm_k<256, 256, false, true>
      <<<MM / 64, 256, 0, stream>>>(ctx_dcn, W_out, nullptr, out, lng, lnb);
}

// Round 3
// 248.566 us; speedup vs baseline: 1.9850x; 1.5615x over previous
//
#include <hip/hip_runtime.h>
#include <math.h>

// Problem constants
constexpr int NBATCH = 2, HH = 128, WW = 128, CC = 256, GC = 64;
constexpr int PP = 9, OMW = 108;            // om width = G*P*3 = 108
constexpr int MM = NBATCH * HH * WW;        // 32768 pixels
constexpr int BTCOLS = 640;                 // 256 (W_in) + 128 (W_om pad) + 256 (W_out)

using bf8 = __attribute__((ext_vector_type(8))) short;    // 8 bf16 = 4 VGPR
using f32x4 = __attribute__((ext_vector_type(4))) float;  // 4 f32 accum

__device__ __forceinline__ short f2bf(float x) {
  unsigned u = __builtin_bit_cast(unsigned, x);
  unsigned r = (u + 0x7fffu + ((u >> 16) & 1u)) >> 16;  // round-nearest-even
  return (short)r;
}
__device__ __forceinline__ float bf2f(short h) {
  unsigned u = ((unsigned)(unsigned short)h) << 16;
  return __builtin_bit_cast(float, u);
}

// ---------------------------------------------------------------------------
// Weight prep: transpose W (K-major -> col-major, K contiguous) and split
// f32 = hi(bf16) + lo(bf16). Bt layout: cols [0,256)=W_in^T, [256,384)=W_om^T
// (zero-padded 108->128), [384,640)=W_out^T. Row stride = 256 (K).
// ---------------------------------------------------------------------------
__global__ __launch_bounds__(256) void prep_kernel(
    const float* __restrict__ Win, const float* __restrict__ Wom,
    const float* __restrict__ Wout, short* __restrict__ Bh,
    short* __restrict__ Bl) {
  int gid = blockIdx.x * 256 + threadIdx.x;  // over BTCOLS*256
  int col = gid >> 8, k = gid & 255;
  float w;
  if (col < 256)
    w = Win[k * 256 + col];
  else if (col < 384) {
    int c = col - 256;
    w = (c < OMW) ? Wom[k * OMW + c] : 0.f;
  } else {
    int c = col - 384;
    w = Wout[k * 256 + c];
  }
  short h = f2bf(w);
  short l = f2bf(w - bf2f(h));
  Bh[gid] = h;
  Bl[gid] = l;
}

// ---------------------------------------------------------------------------
// Depthwise 3x3 conv (pad 1) + bias. One thread per (pixel, channel-quad).
// ---------------------------------------------------------------------------
__global__ __launch_bounds__(256) void dwconv_kernel(
    const float* __restrict__ x, const float* __restrict__ k,
    const float* __restrict__ b, float* __restrict__ y) {
  int gid = blockIdx.x * 256 + threadIdx.x;  // over MM * 64
  int q = gid & 63;
  int m = gid >> 6;
  int c = q * 4;
  int w = m & 127, h = (m >> 7) & 127, n = m >> 14;
  float4 acc = *(const float4*)&b[c];
#pragma unroll
  for (int dy = 0; dy < 3; ++dy) {
    int yy = h + dy - 1;
    if (yy < 0 || yy >= HH) continue;
#pragma unroll
    for (int dx = 0; dx < 3; ++dx) {
      int xx = w + dx - 1;
      if (xx < 0 || xx >= WW) continue;
      float4 v = *(const float4*)&x[(((size_t)n * HH + yy) * WW + xx) * CC + c];
      float4 kk = *(const float4*)&k[(dy * 3 + dx) * CC + c];
      acc.x += v.x * kk.x;
      acc.y += v.y * kk.y;
      acc.z += v.z * kk.z;
      acc.w += v.w * kk.w;
    }
  }
  *(float4*)&y[(size_t)m * CC + c] = acc;
}

// ---------------------------------------------------------------------------
// MFMA GEMM with bf16x3 split precision: Co = A(f32)[M,256] @ W[256,NOUT].
// A split hi/lo on the fly during staging; W pre-split/transposed (Bth/Btl,
// col-major, K contiguous, row stride 256).
// Tile: BM=128 x BN (128 or 256), BK=32. Waves of 64x64 (4x4 frags of
// 16x16x32). LDS K-innermost -> all frag ds_read_b128 conflict-free.
// Fragment maps (m89-verified convention): A: row=lane&15, k=(lane>>4)*8+j;
// B: col=lane&15, k same; D: col=lane&15, row=(lane>>4)*4+reg.
// LN variant fuses LayerNorm(256 cols) + exact GELU.
// ---------------------------------------------------------------------------
template <int BN, int NOUT, bool BIAS, bool LN>
__global__ __launch_bounds__(BN == 256 ? 512 : 256) void mgemm(
    const float* __restrict__ A, const short* __restrict__ Bth,
    const short* __restrict__ Btl, const float* __restrict__ bias,
    float* __restrict__ Co, const float* __restrict__ lng,
    const float* __restrict__ lnb) {
  constexpr int BM = 128, BK = 32;
  constexpr int NT = (BN == 256) ? 512 : 256;
  constexpr int WN = BN / 64;  // waves along n
  __shared__ __align__(16) short Ah[BM][BK], Al[BM][BK];
  __shared__ __align__(16) short Bh[BN][BK], Bl[BN][BK];
  const int t = threadIdx.x;
  const int lane = t & 63, wid = t >> 6;
  const int wr = wid / WN, wc = wid % WN;
  const int l15 = lane & 15, l4 = lane >> 4;
  int mb, nb;
  if constexpr (BN == 128 && NOUT == 256) {
    mb = (int)(blockIdx.x >> 1) * BM;
    nb = (int)(blockIdx.x & 1) * 128;
  } else {
    mb = (int)blockIdx.x * BM;
    nb = 0;
  }

  f32x4 acc[4][4];
#pragma unroll
  for (int r = 0; r < 4; ++r)
#pragma unroll
    for (int n = 0; n < 4; ++n) acc[r][n] = (f32x4){0.f, 0.f, 0.f, 0.f};

  for (int ks = 0; ks < 256; ks += BK) {
    // Stage A tile (f32 -> bf16 hi/lo), layout [row][k] K-contiguous
#pragma unroll
    for (int i = 0; i < (BM * BK / 4) / NT; ++i) {
      int idx = t + NT * i;
      int row = idx >> 3, kq = idx & 7;
      float4 v = *(const float4*)&A[(size_t)(mb + row) * 256 + ks + kq * 4];
      short4 h = make_short4(f2bf(v.x), f2bf(v.y), f2bf(v.z), f2bf(v.w));
      short4 l =
          make_short4(f2bf(v.x - bf2f(h.x)), f2bf(v.y - bf2f(h.y)),
                      f2bf(v.z - bf2f(h.z)), f2bf(v.w - bf2f(h.w)));
      *(short4*)&Ah[row][kq * 4] = h;
      *(short4*)&Al[row][kq * 4] = l;
    }
    // Stage B tile (straight bf16 copy, already transposed)
#pragma unroll
    for (int i = 0; i < (BN * 4) / NT; ++i) {
      int idx = t + NT * i;
      int col = idx >> 2, q = idx & 3;
      *(bf8*)&Bh[col][q * 8] =
          *(const bf8*)&Bth[(size_t)(nb + col) * 256 + ks + q * 8];
      *(bf8*)&Bl[col][q * 8] =
          *(const bf8*)&Btl[(size_t)(nb + col) * 256 + ks + q * 8];
    }
    __syncthreads();

    bf8 ah[4], al[4], bh[4], bl[4];
#pragma unroll
    for (int r = 0; r < 4; ++r) {
      int row = wr * 64 + r * 16 + l15;
      ah[r] = *(const bf8*)&Ah[row][l4 * 8];
      al[r] = *(const bf8*)&Al[row][l4 * 8];
    }
#pragma unroll
    for (int n = 0; n < 4; ++n) {
      int col = wc * 64 + n * 16 + l15;
      bh[n] = *(const bf8*)&Bh[col][l4 * 8];
      bl[n] = *(const bf8*)&Bl[col][l4 * 8];
    }
#pragma unroll
    for (int r = 0; r < 4; ++r)
#pragma unroll
      for (int n = 0; n < 4; ++n) {
        acc[r][n] =
            __builtin_amdgcn_mfma_f32_16x16x32_bf16(al[r], bh[n], acc[r][n], 0, 0, 0);
        acc[r][n] =
            __builtin_amdgcn_mfma_f32_16x16x32_bf16(ah[r], bl[n], acc[r][n], 0, 0, 0);
        acc[r][n] =
            __builtin_amdgcn_mfma_f32_16x16x32_bf16(ah[r], bh[n], acc[r][n], 0, 0, 0);
      }
    __syncthreads();
  }

  if constexpr (LN) {
    __shared__ float red[BM][2];
    __shared__ float mu_s[BM], rs_s[BM];
    if (t < BM) {
      red[t][0] = 0.f;
      red[t][1] = 0.f;
    }
    __syncthreads();
#pragma unroll
    for (int r = 0; r < 4; ++r) {
#pragma unroll
      for (int reg = 0; reg < 4; ++reg) {
        float s = 0.f, ss = 0.f;
#pragma unroll
        for (int n = 0; n < 4; ++n) {
          float v = acc[r][n][reg];
          s += v;
          ss += v * v;
        }
#pragma unroll
        for (int m = 1; m < 16; m <<= 1) {
          s += __shfl_xor(s, m);
          ss += __shfl_xor(ss, m);
        }
        if (l15 == 0) {
          int row = wr * 64 + r * 16 + l4 * 4 + reg;
          atomicAdd(&red[row][0], s);
          atomicAdd(&red[row][1], ss);
        }
      }
    }
    __syncthreads();
    if (t < BM) {
      float mu = red[t][0] * (1.f / 256.f);
      float var = red[t][1] * (1.f / 256.f) - mu * mu;
      mu_s[t] = mu;
      rs_s[t] = rsqrtf(var + 1e-5f);
    }
    __syncthreads();
#pragma unroll
    for (int r = 0; r < 4; ++r)
#pragma unroll
      for (int reg = 0; reg < 4; ++reg) {
        int rloc = wr * 64 + r * 16 + l4 * 4 + reg;
        int row = mb + rloc;
        float mu = mu_s[rloc], rs = rs_s[rloc];
#pragma unroll
        for (int n = 0; n < 4; ++n) {
          int col = nb + wc * 64 + n * 16 + l15;
          float v = (acc[r][n][reg] - mu) * rs * lng[col] + lnb[col];
          Co[(size_t)row * NOUT + col] =
              0.5f * v * (1.f + erff(v * 0.70710678118654752f));
        }
      }
  } else {
#pragma unroll
    for (int r = 0; r < 4; ++r)
#pragma unroll
      for (int reg = 0; reg < 4; ++reg) {
        int row = mb + wr * 64 + r * 16 + l4 * 4 + reg;
#pragma unroll
        for (int n = 0; n < 4; ++n) {
          int col = nb + wc * 64 + n * 16 + l15;
          if (NOUT == BN * (256 / BN) || col < NOUT) {  // guard only NOUT=108
            float v = acc[r][n][reg];
            if constexpr (BIAS) v += bias[col];
            if (col < NOUT) Co[(size_t)row * NOUT + col] = v;
          }
        }
      }
  }
}

// ---------------------------------------------------------------------------
// Deformable bilinear sampling + mask-weighted sum over P taps.
// One thread per (pixel, channel-quad): float4 gathers; branchless clamp.
// ---------------------------------------------------------------------------
__global__ __launch_bounds__(256) void sample_kernel(
    const float* __restrict__ val, const float* __restrict__ om,
    float* __restrict__ out) {
  int gid = blockIdx.x * 256 + threadIdx.x;  // over MM * 64
  int q = gid & 63;   // channel-quad
  int m = gid >> 6;   // pixel
  int g = q >> 4;     // group
  int w = m & 127, h = (m >> 7) & 127, n = m >> 14;
  const float* omp = om + m * OMW + g * 27;
  const float* vb = val + (n << 22) + (q << 2);
  float bx = (float)(w + 1), by = (float)(h + 1);
  float4 acc = make_float4(0.f, 0.f, 0.f, 0.f);

#pragma unroll
  for (int p = 0; p < PP; ++p) {
    float px = bx + 0.5f * ((float)(p % 3 - 1) + omp[2 * p]);
    float py = by + 0.5f * ((float)(p / 3 - 1) + omp[2 * p + 1]);
    float mk = omp[18 + p];
    float x0f = floorf(px), y0f = floorf(py);
    int x0 = (int)x0f, y0 = (int)y0f;
    float wx1 = px - x0f, wy1 = py - y0f;
    float wx0 = 1.f - wx1, wy0 = 1.f - wy1;
    float4 s = make_float4(0.f, 0.f, 0.f, 0.f);
#define CORNER(XC, YC, WT)                                            \
  {                                                                   \
    int xc = (XC), yc = (YC);                                         \
    int xi = min(max(xc, 1), 128), yi = min(max(yc, 1), 128);         \
    float wt = ((xc == xi) && (yc == yi)) ? (WT) : 0.f;               \
    const float4 v =                                                  \
        *(const float4*)&vb[(((yi - 1) << 7) + (xi - 1)) << 8];       \
    s.x += v.x * wt;                                                  \
    s.y += v.y * wt;                                                  \
    s.z += v.z * wt;                                                  \
    s.w += v.w * wt;                                                  \
  }
    CORNER(x0, y0, wx0 * wy0);
    CORNER(x0 + 1, y0, wx1 * wy0);
    CORNER(x0, y0 + 1, wx0 * wy1);
    CORNER(x0 + 1, y0 + 1, wx1 * wy1);
#undef CORNER
    acc.x += mk * s.x;
    acc.y += mk * s.y;
    acc.z += mk * s.z;
    acc.w += mk * s.w;
  }
  *(float4*)&out[((size_t)m << 8) + (q << 2)] = acc;
}

// ---------------------------------------------------------------------------
extern "C" void kernel_launch(void* const* d_in, const int* in_sizes, int n_in,
                              void* d_out, int out_size, void* d_ws,
                              size_t ws_size, hipStream_t stream) {
  (void)in_sizes;
  (void)n_in;
  (void)out_size;
  (void)ws_size;
  const float* sampled = (const float*)d_in[0];
  const float* ctxin = (const float*)d_in[1];
  const float* W_in = (const float*)d_in[2];
  const float* b_in = (const float*)d_in[3];
  const float* dwk = (const float*)d_in[4];
  const float* dwb = (const float*)d_in[5];
  const float* W_om = (const float*)d_in[6];
  const float* b_om = (const float*)d_in[7];
  const float* W_out = (const float*)d_in[8];
  const float* lng = (const float*)d_in[9];
  const float* lnb = (const float*)d_in[10];
  float* out = (float*)d_out;

  float* ws = (float*)d_ws;
  float* value = ws;                          // MM*256 f32
  float* omb = value + (size_t)MM * CC;       // MM*108 f32
  float* ctx_dcn = omb + (size_t)MM * OMW;    // MM*256 f32 (ctx, then dcn)
  short* Bth = (short*)(ctx_dcn + (size_t)MM * CC);  // BTCOLS*256 bf16
  short* Btl = Bth + (size_t)BTCOLS * 256;

  // 0. weight transpose + bf16 hi/lo split
  prep_kernel<<<BTCOLS, 256, 0, stream>>>(W_in, W_om, W_out, Bth, Btl);
  // 1. depthwise conv -> ctx
  dwconv_kernel<<<MM * 64 / 256, 256, 0, stream>>>(ctxin, dwk, dwb, ctx_dcn);
  // 2. om = ctx @ W_om + b_om   (BN=128 covers padded 108 cols)
  mgemm<128, 108, true, false><<<MM / 128, 256, 0, stream>>>(
      ctx_dcn, Bth + 256 * 256, Btl + 256 * 256, b_om, omb, nullptr, nullptr);
  // 3. value = sampled_feat @ W_in + b_in  (2 n-blocks of 128)
  mgemm<128, 256, true, false><<<2 * (MM / 128), 256, 0, stream>>>(
      sampled, Bth, Btl, b_in, value, nullptr, nullptr);
  // 4. deformable sampling -> dcn (reuses ctx buffer)
  sample_kernel<<<MM * 64 / 256, 256, 0, stream>>>(value, omb, ctx_dcn);
  // 5. out = GELU(LN(dcn @ W_out))
  mgemm<256, 256, false, true><<<MM / 128, 512, 0, stream>>>(
      ctx_dcn, Bth + 384 * 256, Btl + 384 * 256, nullptr, out, lng, lnb);
}